// Round 10
// baseline (1226.612 us; speedup 1.0000x reference)
//
#include <hip/hip_runtime.h>

// DRNet, R10: T-CHUNKED two-pass (R9's 1.07GB workspace didn't fit -> fused
// fallback ran). Per 32-step chunk: drnet_rng fills a 128MB noise slab (fits
// L3), then drnet_scan32 advances the recurrence 32 steps reading the slab;
// latent carried across chunks as exact fp32 in ws (4MB) with deterministic
// fp16 hi/lo LDS rebuild -> bit-identical to the uninterrupted R8 run
// (absmax 2.0). Needs ws >= 132MB, else falls back to proven R8 fused
// (988us). Rationale: fused is VALU-issue-bound (VALUBusy 91%) with ~355us
// of cipher work; a dedicated branch-light RNG kernel issues at ~95+% and
// the RNG-free scan is bound by its own ~12-30us/chunk LDS/MFMA pipeline.

#define TSTEPS 256
#define HDIM   256
#define ROWS   16
#define LSTR   264            // shorts per tile row (pad 8)
#define TILE   (ROWS * LSTR)  // 4224 shorts = 8448 B per level
#define XSTR   260
#define SCH    32             // steps per chunk

typedef _Float16 half8 __attribute__((ext_vector_type(8)));
typedef __attribute__((ext_vector_type(4))) float float4v;

struct U2 { unsigned x, y; };

__device__ __forceinline__ void tfround(unsigned &x0, unsigned &x1, const int r) {
  x0 += x1;
  x1 = __builtin_rotateleft32(x1, r);
  x1 ^= x0;
}

// Threefry-2x32, 20 rounds (Random123 / JAX threefry2x32_p)
__device__ __forceinline__ U2 threefry(unsigned k0, unsigned k1, unsigned x0, unsigned x1) {
  unsigned k2 = k0 ^ k1 ^ 0x1BD11BDAu;
  x0 += k0; x1 += k1;
  tfround(x0,x1,13); tfround(x0,x1,15); tfround(x0,x1,26); tfround(x0,x1,6);
  x0 += k1; x1 += k2 + 1u;
  tfround(x0,x1,17); tfround(x0,x1,29); tfround(x0,x1,16); tfround(x0,x1,24);
  x0 += k2; x1 += k0 + 2u;
  tfround(x0,x1,13); tfround(x0,x1,15); tfround(x0,x1,26); tfround(x0,x1,6);
  x0 += k0; x1 += k1 + 3u;
  tfround(x0,x1,17); tfround(x0,x1,29); tfround(x0,x1,16); tfround(x0,x1,24);
  x0 += k1; x1 += k2 + 4u;
  tfround(x0,x1,13); tfround(x0,x1,15); tfround(x0,x1,26); tfround(x0,x1,6);
  x0 += k2; x1 += k0 + 5u;
  return {x0, x1};
}

// JAX uniform(lo=nextafter(-1,0), 1) -> sqrt(2)*erf_inv(u), XLA ErfInv32.
__device__ __forceinline__ float jax_normal_from_bits(unsigned bits) {
#pragma clang fp contract(off)
  const float LO = __builtin_bit_cast(float, 0xBF7FFFFFu); // nextafter(-1,0)
  float f = __builtin_bit_cast(float, (bits >> 9) | 0x3f800000u) - 1.0f;
  float u = fmaf(f, 2.0f, LO);
  u = fmaxf(u, LO);
  float t1 = u * u;             // rounded u^2 (as XLA's x*x)
  float s  = 1.0f - t1;         // Sterbenz-exact in the tail; unfused
  float w  = -0.6931471805599453f * __builtin_amdgcn_logf(s);
  float p;
  if (w < 5.0f) {
    float z = w - 2.5f;
    p = 2.81022636e-08f;
    p = fmaf(p, z, 3.43273939e-07f);
    p = fmaf(p, z, -3.5233877e-06f);
    p = fmaf(p, z, -4.39150654e-06f);
    p = fmaf(p, z, 0.00021858087f);
    p = fmaf(p, z, -0.00125372503f);
    p = fmaf(p, z, -0.00417768164f);
    p = fmaf(p, z, 0.246640727f);
    p = fmaf(p, z, 1.50140941f);
  } else {
    float z = sqrtf(w) - 3.0f;
    p = -0.000200214257f;
    p = fmaf(p, z, 0.000100950558f);
    p = fmaf(p, z, 0.00134934322f);
    p = fmaf(p, z, -0.00367342844f);
    p = fmaf(p, z, 0.00573950773f);
    p = fmaf(p, z, -0.0076224613f);
    p = fmaf(p, z, 0.00943887047f);
    p = fmaf(p, z, 1.00167406f);
    p = fmaf(p, z, 2.83297682f);
  }
  return 1.4142135623730951f * (p * u);
}

__device__ __forceinline__ float4v mfma_f16(half8 a, half8 b, float4v c) {
  return __builtin_amdgcn_mfma_f32_16x16x32_f16(a, b, c, 0, 0, 0);
}

// ---------------------------------------------------------------------------
// Pass 1 (per chunk): noise for steps [t0, t0+32) -> slab (32 x 4MB).
// Slab float index within a step: i = wg*2^12 + wv*2^8 + q*2^6 + c*2^2 + r,
// matching the scan's one-dwordx4-per-lane read. j = b*256+g.
// ---------------------------------------------------------------------------
__global__ __launch_bounds__(256, 4)
void drnet_rng(float* __restrict__ slab, int t0) {
  const unsigned bid = blockIdx.x;          // 0..2047; 64 blocks per step
  const unsigned ts  = bid >> 6;            // local step 0..31
  U2 kk = threefry(0u, 42u, 0u, (unsigned)t0 + ts);
  unsigned kA = (unsigned)__builtin_amdgcn_readfirstlane((int)kk.x);
  unsigned kB = (unsigned)__builtin_amdgcn_readfirstlane((int)kk.y);
  const unsigned e20 = (bid & 63u) * 16384u + threadIdx.x * 4u;
  float* dst = slab + ((size_t)ts << 20);
  #pragma unroll 2
  for (unsigned s = 0; s < 16; ++s) {
    unsigned e0 = e20 + (s << 10);
    unsigned b0 = ((e0 >> 12) & 255u) * 16u + ((e0 >> 6) & 3u) * 4u;
    unsigned g  = ((e0 >> 8) & 15u) * 16u + ((e0 >> 2) & 15u);
    unsigned j0 = b0 * 256u + g;
    float4v v;
    #pragma unroll
    for (int r = 0; r < 4; ++r) {
      U2 rr = threefry(kA, kB, 0u, j0 + ((unsigned)r << 8));
      v[r] = jax_normal_from_bits(rr.x ^ rr.y);
    }
    *(float4v*)(dst + e0) = v;
  }
}

// ---------------------------------------------------------------------------
// Pass 2 (per chunk): 32 scan steps; latent restored from / saved to latsave
// (exact fp32 -> bit-identical to uninterrupted run).
// ---------------------------------------------------------------------------
__global__ __launch_bounds__(1024, 4)
void drnet_scan32(const float* __restrict__ flat_img,
                  const float* __restrict__ W_ih,
                  const float* __restrict__ W_hh,
                  const float* __restrict__ b_ih,
                  const float* __restrict__ b_hh,
                  const float* __restrict__ slab,
                  float* __restrict__ latsave,
                  float* __restrict__ out,
                  int t0, int first, int last)
{
  // >81920 B -> 1 block/CU -> exactly 4 waves/EU -> 128-reg budget (proven)
  __shared__ __align__(16) char lds_pool[86016];
  float* x_sh = (float*)lds_pool;                 // 16640 B
  short* latp = (short*)(lds_pool + 16640);       // 2 buf x 2 lv x TILE

  const int tid  = threadIdx.x;
  const int wg   = blockIdx.x;
  const int wv   = tid >> 6;
  const int lane = tid & 63;
  const int q    = lane >> 4;
  const int c    = lane & 15;

  { // stage x
    int i = tid * 4;
    int m = i >> 8;
    float4v v = *(const float4v*)(flat_img + (size_t)wg * (ROWS*TSTEPS) + i);
    *(float4v*)&x_sh[m * XSTR + (i & 255)] = v;
  }

  const int g = wv*16 + c;
  float lat[4] = {0.f, 0.f, 0.f, 0.f};
  const unsigned jbase = ((unsigned)(wg*ROWS + q*4) << 8) + (unsigned)g;
  const int aoff = c * LSTR + q * 8;
  const int woff = (q*4) * LSTR + wv*16 + c;

  if (first) { // zero latent LDS (both buffers); lat already zero
    int* p0 = (int*)latp;
    for (int i = tid; i < 2 * TILE; i += 1024) p0[i] = 0;
  } else {     // restore fp32 master, rebuild buf0 hi/lo deterministically
    #pragma unroll
    for (int r = 0; r < 4; ++r) {
      float nl = latsave[jbase + ((unsigned)r << 8)];
      lat[r] = nl;
      _Float16 hh = (_Float16)nl;
      _Float16 ll = (_Float16)((nl - (float)hh) * 2048.0f);
      short* wp = latp + woff + r*LSTR;
      wp[0]    = __builtin_bit_cast(short, hh);
      wp[TILE] = __builtin_bit_cast(short, ll);
    }
  }

  // persistent W_hh fragments: 2-level fp16 split (level-1 scaled 2^11)
  half8 Wh[8], Wl[8];
  const float bias = b_ih[g] + b_hh[g];
  const float wih  = W_ih[g];
  #pragma unroll
  for (int kk = 0; kk < 8; ++kk) {
    const float* wp = W_hh + g*HDIM + kk*32 + q*8;
    float4v w0 = *(const float4v*)wp;
    float4v w1 = *(const float4v*)(wp + 4);
    half8 h8, l8;
    #pragma unroll
    for (int j2 = 0; j2 < 4; ++j2) {
      float f0 = w0[j2], f1 = w1[j2];
      _Float16 h0 = (_Float16)f0, h1 = (_Float16)f1;
      _Float16 l0 = (_Float16)((f0 - (float)h0) * 2048.0f);
      _Float16 l1 = (_Float16)((f1 - (float)h1) * 2048.0f);
      h8[j2] = h0; h8[j2+4] = h1;
      l8[j2] = l0; l8[j2+4] = l1;
    }
    Wh[kk] = h8; Wl[kk] = l8;
  }

  // noise: one float4 per lane per step; step stride = 2^20 floats = 2^18 f4
  const float4v* np = (const float4v*)slab +
      ((unsigned)wg*1024u + (unsigned)wv*64u + (unsigned)lane);
  float4v nz_pend = np[0];

  __syncthreads();

  for (int ts = 0; ts < SCH; ++ts) {
    float4v nz = nz_pend;
    int tn = ts + 1 < SCH ? ts + 1 : ts;          // clamp: stay inside slab
    nz_pend = np[(size_t)tn * 262144u];

    int t = t0 + ts;
    float tsf = (float)(TSTEPS - t);
    float a_t = (tsf + 1.0f) / 257.0f;
    float escale = 0.1f * sqrtf(a_t * (1.0f - a_t));  // exactly 0 at t=0

    const short* rb = latp + (ts & 1) * (2*TILE) + aoff;
    short*       wb = latp + ((ts + 1) & 1) * (2*TILE) + woff;

    // AhWh -> aa ; (AlWh + AhWl) -> ab (one 2^11 scale); drop AlWl ~2^-24
    float4v aa = {0.f, 0.f, 0.f, 0.f};
    float4v ab = {0.f, 0.f, 0.f, 0.f};
    #pragma unroll
    for (int kk = 0; kk < 8; ++kk) {
      half8 ah = *(const half8*)(rb + 0*TILE + kk*32);
      half8 al = *(const half8*)(rb + 1*TILE + kk*32);
      aa = mfma_f16(ah, Wh[kk], aa);
      ab = mfma_f16(al, Wh[kk], ab);
      ab = mfma_f16(ah, Wl[kk], ab);
    }

    #pragma unroll
    for (int r = 0; r < 4; ++r) lat[r] = fmaf(escale, nz[r], lat[r]);

    float xr[4];
    #pragma unroll
    for (int r = 0; r < 4; ++r) xr[r] = x_sh[(q*4 + r) * XSTR + t];

    #pragma unroll
    for (int r = 0; r < 4; ++r) {
      float d = aa[r] + ab[r] * (1.0f / 2048.0f);
      float pre = d + fmaf(xr[r], wih, bias);
      float h;
      if (__builtin_fabsf(pre) >= 7.90531110763549805f) {
        h = pre > 0.0f ? 1.0f : -1.0f;     // XLA tanh clamp
      } else {
        float e = __builtin_amdgcn_exp2f(pre * 2.8853900817779268f);
        h = fmaf(-2.0f, __builtin_amdgcn_rcpf(e + 1.0f), 1.0f);
      }
      float nl = lat[r] + xr[r] + h;
      lat[r] = nl;
      _Float16 hh = (_Float16)nl;
      _Float16 ll = (_Float16)((nl - (float)hh) * 2048.0f);
      short* wp = wb + r*LSTR;
      wp[0]    = __builtin_bit_cast(short, hh);
      wp[TILE] = __builtin_bit_cast(short, ll);
    }
    __syncthreads();
  }

  if (last) {
    #pragma unroll
    for (int r = 0; r < 4; ++r) out[jbase + ((unsigned)r << 8)] = lat[r];
  } else {
    #pragma unroll
    for (int r = 0; r < 4; ++r) latsave[jbase + ((unsigned)r << 8)] = lat[r];
  }
}

// ---------------------------------------------------------------------------
// Fallback: R8 fused kernel (proven: 988us, absmax 2.0) for small ws_size.
// ---------------------------------------------------------------------------
__global__ __launch_bounds__(1024, 4)
void drnet_fused(const float* __restrict__ flat_img,
                 const float* __restrict__ W_ih,
                 const float* __restrict__ W_hh,
                 const float* __restrict__ b_ih,
                 const float* __restrict__ b_hh,
                 float* __restrict__ out)
{
  __shared__ __align__(16) char lds_pool[86016];
  float*    x_sh    = (float*)lds_pool;
  unsigned* keys_sh = (unsigned*)(lds_pool + 16640);
  short*    latp    = (short*)(lds_pool + 18688);

  const int tid  = threadIdx.x;
  const int wg   = blockIdx.x;
  const int wv   = tid >> 6;
  const int lane = tid & 63;
  const int q    = lane >> 4;
  const int c    = lane & 15;

  if (tid < TSTEPS) {
    U2 kk = threefry(0u, 42u, 0u, (unsigned)tid);
    keys_sh[2*tid]   = kk.x;
    keys_sh[2*tid+1] = kk.y;
  }
  {
    int i = tid * 4;
    int m = i >> 8;
    float4v v = *(const float4v*)(flat_img + (size_t)wg * (ROWS*TSTEPS) + i);
    *(float4v*)&x_sh[m * XSTR + (i & 255)] = v;
  }
  {
    int* p0 = (int*)latp;
    for (int i = tid; i < 2 * TILE; i += 1024) p0[i] = 0;
  }

  half8 Wh[8], Wl[8];
  const int g = wv*16 + c;
  const float bias = b_ih[g] + b_hh[g];
  const float wih  = W_ih[g];
  #pragma unroll
  for (int kk = 0; kk < 8; ++kk) {
    const float* wp = W_hh + g*HDIM + kk*32 + q*8;
    float4v w0 = *(const float4v*)wp;
    float4v w1 = *(const float4v*)(wp + 4);
    half8 h8, l8;
    #pragma unroll
    for (int j2 = 0; j2 < 4; ++j2) {
      float f0 = w0[j2], f1 = w1[j2];
      _Float16 h0 = (_Float16)f0, h1 = (_Float16)f1;
      _Float16 l0 = (_Float16)((f0 - (float)h0) * 2048.0f);
      _Float16 l1 = (_Float16)((f1 - (float)h1) * 2048.0f);
      h8[j2] = h0; h8[j2+4] = h1;
      l8[j2] = l0; l8[j2+4] = l1;
    }
    Wh[kk] = h8; Wl[kk] = l8;
  }

  float lat[4] = {0.f, 0.f, 0.f, 0.f};
  const unsigned jbase = ((unsigned)(wg*ROWS + q*4) << 8) + (unsigned)g;
  const int aoff = c * LSTR + q * 8;
  const int woff = (q*4) * LSTR + wv*16 + c;

  __syncthreads();

  for (int t = 0; t < TSTEPS; ++t) {
    unsigned kA = (unsigned)__builtin_amdgcn_readfirstlane((int)keys_sh[2*t]);
    unsigned kB = (unsigned)__builtin_amdgcn_readfirstlane((int)keys_sh[2*t+1]);

    float tsf = (float)(TSTEPS - t);
    float a_t = (tsf + 1.0f) / 257.0f;
    float escale = 0.1f * sqrtf(a_t * (1.0f - a_t));

    const short* rb = latp + (t & 1) * (2*TILE) + aoff;
    short*       wb = latp + ((t + 1) & 1) * (2*TILE) + woff;

    float4v aa = {0.f, 0.f, 0.f, 0.f};
    float4v ab = {0.f, 0.f, 0.f, 0.f};
    #pragma unroll
    for (int kk = 0; kk < 8; ++kk) {
      half8 ah = *(const half8*)(rb + 0*TILE + kk*32);
      half8 al = *(const half8*)(rb + 1*TILE + kk*32);
      aa = mfma_f16(ah, Wh[kk], aa);
      ab = mfma_f16(al, Wh[kk], ab);
      ab = mfma_f16(ah, Wl[kk], ab);
      if (kk < 4) {
        unsigned j = jbase + (unsigned)(kk << 8);
        U2 rr = threefry(kA, kB, 0u, j);
        float nrm = jax_normal_from_bits(rr.x ^ rr.y);
        lat[kk] = fmaf(escale, nrm, lat[kk]);
      }
    }

    float xr[4];
    #pragma unroll
    for (int r = 0; r < 4; ++r) xr[r] = x_sh[(q*4 + r) * XSTR + t];

    #pragma unroll
    for (int r = 0; r < 4; ++r) {
      float d = aa[r] + ab[r] * (1.0f / 2048.0f);
      float pre = d + fmaf(xr[r], wih, bias);
      float h;
      if (__builtin_fabsf(pre) >= 7.90531110763549805f) {
        h = pre > 0.0f ? 1.0f : -1.0f;
      } else {
        float e = __builtin_amdgcn_exp2f(pre * 2.8853900817779268f);
        h = fmaf(-2.0f, __builtin_amdgcn_rcpf(e + 1.0f), 1.0f);
      }
      float nl = lat[r] + xr[r] + h;
      lat[r] = nl;
      _Float16 hh = (_Float16)nl;
      _Float16 ll = (_Float16)((nl - (float)hh) * 2048.0f);
      short* wp = wb + r*LSTR;
      wp[0]    = __builtin_bit_cast(short, hh);
      wp[TILE] = __builtin_bit_cast(short, ll);
    }
    __syncthreads();
  }

  #pragma unroll
  for (int r = 0; r < 4; ++r)
    out[jbase + (unsigned)(r << 8)] = lat[r];
}

extern "C" void kernel_launch(void* const* d_in, const int* in_sizes, int n_in,
                              void* d_out, int out_size, void* d_ws, size_t ws_size,
                              hipStream_t stream) {
  // inputs: [0]=T (int, =256), [1]=flat_img (4096x256 f32), [2]=W_ih (256x1),
  // [3]=W_hh (256x256), [4]=b_ih (256), [5]=b_hh (256)
  (void)in_sizes; (void)n_in; (void)out_size;
  const float* flat_img = (const float*)d_in[1];
  const float* W_ih     = (const float*)d_in[2];
  const float* W_hh     = (const float*)d_in[3];
  const float* b_ih     = (const float*)d_in[4];
  const float* b_hh     = (const float*)d_in[5];
  // need: 4MB latent save + 32-step slab (128MB) = 132MB
  const size_t need = ((size_t)SCH << 20) * 4 + ((size_t)1 << 22);
  if (ws_size >= need) {
    float* latsave = (float*)d_ws;
    float* slab    = latsave + (1u << 20);
    for (int ch = 0; ch < TSTEPS / SCH; ++ch) {
      drnet_rng<<<dim3(SCH * 64), dim3(256), 0, stream>>>(slab, ch * SCH);
      drnet_scan32<<<dim3(4096 / ROWS), dim3(1024), 0, stream>>>(
          flat_img, W_ih, W_hh, b_ih, b_hh, slab, latsave, (float*)d_out,
          ch * SCH, ch == 0, ch == (TSTEPS / SCH - 1));
    }
  } else {
    drnet_fused<<<dim3(4096 / ROWS), dim3(1024), 0, stream>>>(
        flat_img, W_ih, W_hh, b_ih, b_hh, (float*)d_out);
  }
}

// Round 11
// 962.706 us; speedup vs baseline: 1.2741x; 1.2741x over previous
//
#include <hip/hip_runtime.h>

// DRNet, R11: fused-only (R10's two-pass regressed: RNG kernel measured the
// cipher+erfinv wall at 697us of ~92%-efficient VALU issue; total VALU issue
// ~900us is partition-invariant, and the fused kernel's 4-wave/SIMD TLP
// already hides MFMA/LDS under it at 91% busy -> fused is the right shape).
// R11 trims vs R8 fused (988us):
//  - escale precomputed into a 256-entry LDS table (identical fp32 ops) --
//    removes per-step per-lane tsf/a_t/sqrt (~6 inst incl quarter-rate sqrt)
//  - x staged TRANSPOSED (x_tr[t][row]) -> per-step 4x strided ds_read_b32
//    becomes one broadcast ds_read_b128
// Numerics bit-identical to R8 (absmax 2.0): same cipher, erfinv, fp16
// 2-level split (level-1 scaled 2^11), same application order.

#define TSTEPS 256
#define HDIM   256
#define ROWS   16
#define LSTR   264            // shorts per tile row (pad 8)
#define TILE   (ROWS * LSTR)  // 4224 shorts = 8448 B per level

typedef _Float16 half8 __attribute__((ext_vector_type(8)));
typedef __attribute__((ext_vector_type(4))) float float4v;

struct U2 { unsigned x, y; };

__device__ __forceinline__ void tfround(unsigned &x0, unsigned &x1, const int r) {
  x0 += x1;
  x1 = __builtin_rotateleft32(x1, r);
  x1 ^= x0;
}

// Threefry-2x32, 20 rounds (Random123 / JAX threefry2x32_p)
__device__ __forceinline__ U2 threefry(unsigned k0, unsigned k1, unsigned x0, unsigned x1) {
  unsigned k2 = k0 ^ k1 ^ 0x1BD11BDAu;
  x0 += k0; x1 += k1;
  tfround(x0,x1,13); tfround(x0,x1,15); tfround(x0,x1,26); tfround(x0,x1,6);
  x0 += k1; x1 += k2 + 1u;
  tfround(x0,x1,17); tfround(x0,x1,29); tfround(x0,x1,16); tfround(x0,x1,24);
  x0 += k2; x1 += k0 + 2u;
  tfround(x0,x1,13); tfround(x0,x1,15); tfround(x0,x1,26); tfround(x0,x1,6);
  x0 += k0; x1 += k1 + 3u;
  tfround(x0,x1,17); tfround(x0,x1,29); tfround(x0,x1,16); tfround(x0,x1,24);
  x0 += k1; x1 += k2 + 4u;
  tfround(x0,x1,13); tfround(x0,x1,15); tfround(x0,x1,26); tfround(x0,x1,6);
  x0 += k2; x1 += k0 + 5u;
  return {x0, x1};
}

// JAX uniform(lo=nextafter(-1,0), 1) -> sqrt(2)*erf_inv(u), XLA ErfInv32.
__device__ __forceinline__ float jax_normal_from_bits(unsigned bits) {
#pragma clang fp contract(off)
  const float LO = __builtin_bit_cast(float, 0xBF7FFFFFu); // nextafter(-1,0)
  float f = __builtin_bit_cast(float, (bits >> 9) | 0x3f800000u) - 1.0f;
  float u = fmaf(f, 2.0f, LO);
  u = fmaxf(u, LO);
  float t1 = u * u;             // rounded u^2 (as XLA's x*x)
  float s  = 1.0f - t1;         // Sterbenz-exact in the tail; unfused
  float w  = -0.6931471805599453f * __builtin_amdgcn_logf(s);
  float p;
  if (w < 5.0f) {
    float z = w - 2.5f;
    p = 2.81022636e-08f;
    p = fmaf(p, z, 3.43273939e-07f);
    p = fmaf(p, z, -3.5233877e-06f);
    p = fmaf(p, z, -4.39150654e-06f);
    p = fmaf(p, z, 0.00021858087f);
    p = fmaf(p, z, -0.00125372503f);
    p = fmaf(p, z, -0.00417768164f);
    p = fmaf(p, z, 0.246640727f);
    p = fmaf(p, z, 1.50140941f);
  } else {
    float z = sqrtf(w) - 3.0f;
    p = -0.000200214257f;
    p = fmaf(p, z, 0.000100950558f);
    p = fmaf(p, z, 0.00134934322f);
    p = fmaf(p, z, -0.00367342844f);
    p = fmaf(p, z, 0.00573950773f);
    p = fmaf(p, z, -0.0076224613f);
    p = fmaf(p, z, 0.00943887047f);
    p = fmaf(p, z, 1.00167406f);
    p = fmaf(p, z, 2.83297682f);
  }
  return 1.4142135623730951f * (p * u);
}

__device__ __forceinline__ float4v mfma_f16(half8 a, half8 b, float4v c) {
  return __builtin_amdgcn_mfma_f32_16x16x32_f16(a, b, c, 0, 0, 0);
}

__global__ __launch_bounds__(1024, 4)
void drnet_fused(const float* __restrict__ flat_img,
                 const float* __restrict__ W_ih,
                 const float* __restrict__ W_hh,
                 const float* __restrict__ b_ih,
                 const float* __restrict__ b_hh,
                 float* __restrict__ out)
{
  // >81920 B -> 1 block/CU -> exactly 4 waves/EU -> 128-reg budget (proven:
  // VGPR=56 + W in AGPRs, zero spill)
  __shared__ __align__(16) char lds_pool[86016];
  float*    x_tr    = (float*)lds_pool;               // [t][row] 16384 B
  unsigned* keys_sh = (unsigned*)(lds_pool + 16384);  // 2048 B
  float*    esc_sh  = (float*)(lds_pool + 18432);     // 1024 B
  short*    latp    = (short*)(lds_pool + 19456);     // 2 buf x 2 lv x TILE

  const int tid  = threadIdx.x;
  const int wg   = blockIdx.x;
  const int wv   = tid >> 6;     // wave owns cols [wv*16, wv*16+16)
  const int lane = tid & 63;
  const int q    = lane >> 4;
  const int c    = lane & 15;

  // partitionable split: key_t = threefry((0,42), (0,t)); escale table
  if (tid < TSTEPS) {
    U2 kk = threefry(0u, 42u, 0u, (unsigned)tid);
    keys_sh[2*tid]   = kk.x;
    keys_sh[2*tid+1] = kk.y;
    float tsf = (float)(TSTEPS - tid);
    float a_t = (tsf + 1.0f) / 257.0f;
    esc_sh[tid] = 0.1f * sqrtf(a_t * (1.0f - a_t));  // exactly 0 at t=0
  }

  { // stage x TRANSPOSED: x_tr[t*16 + row] = flat_img[wg*16+row][t]
    int i = tid * 4;                 // 4 consecutive t of one row
    int m = i >> 8;
    float4v v = *(const float4v*)(flat_img + (size_t)wg * (ROWS*TSTEPS) + i);
    int tbase = i & 255;
    #pragma unroll
    for (int s = 0; s < 4; ++s) x_tr[(tbase + s) * ROWS + m] = v[s];
  }

  { // zero latent: 2 buf x 2 lv x TILE shorts == 2*TILE ints
    int* p0 = (int*)latp;
    for (int i = tid; i < 2 * TILE; i += 1024) p0[i] = 0;
  }

  // persistent W_hh fragments: 2-level fp16 split (level-1 scaled 2^11)
  half8 Wh[8], Wl[8];
  const int g = wv*16 + c;
  const float bias = b_ih[g] + b_hh[g];
  const float wih  = W_ih[g];
  #pragma unroll
  for (int kk = 0; kk < 8; ++kk) {
    const float* wp = W_hh + g*HDIM + kk*32 + q*8;
    float4v w0 = *(const float4v*)wp;
    float4v w1 = *(const float4v*)(wp + 4);
    half8 h8, l8;
    #pragma unroll
    for (int j2 = 0; j2 < 4; ++j2) {
      float f0 = w0[j2], f1 = w1[j2];
      _Float16 h0 = (_Float16)f0, h1 = (_Float16)f1;
      _Float16 l0 = (_Float16)((f0 - (float)h0) * 2048.0f);
      _Float16 l1 = (_Float16)((f1 - (float)h1) * 2048.0f);
      h8[j2] = h0; h8[j2+4] = h1;
      l8[j2] = l0; l8[j2+4] = l1;
    }
    Wh[kk] = h8; Wl[kk] = l8;
  }

  // fp32 master latent: lane owns rows q*4+r (r<4), col g
  float lat[4] = {0.f, 0.f, 0.f, 0.f};
  const unsigned jbase = ((unsigned)(wg*ROWS + q*4) << 8) + (unsigned)g;
  const int aoff = c * LSTR + q * 8;          // A-frag: A[m=lane&15][k=q*8+j]
  const int woff = (q*4) * LSTR + wv*16 + c;  // write base (shorts)

  __syncthreads();

  for (int t = 0; t < TSTEPS; ++t) {
    unsigned kA = (unsigned)__builtin_amdgcn_readfirstlane((int)keys_sh[2*t]);
    unsigned kB = (unsigned)__builtin_amdgcn_readfirstlane((int)keys_sh[2*t+1]);
    float escale = esc_sh[t];

    const short* rb = latp + (t & 1) * (2*TILE) + aoff;
    short*       wb = latp + ((t + 1) & 1) * (2*TILE) + woff;

    // AhWh -> aa ; (AlWh + AhWl) -> ab (one 2^11 scale); drop AlWl ~2^-24.
    // One cipher+erfinv interleaved per kk (kk<4): matrix & VALU pipes overlap.
    float4v aa = {0.f, 0.f, 0.f, 0.f};
    float4v ab = {0.f, 0.f, 0.f, 0.f};
    #pragma unroll
    for (int kk = 0; kk < 8; ++kk) {
      half8 ah = *(const half8*)(rb + 0*TILE + kk*32);
      half8 al = *(const half8*)(rb + 1*TILE + kk*32);
      aa = mfma_f16(ah, Wh[kk], aa);
      ab = mfma_f16(al, Wh[kk], ab);
      ab = mfma_f16(ah, Wl[kk], ab);
      if (kk < 4) {  // compile-time uniform: no divergence
        unsigned j = jbase + ((unsigned)kk << 8);  // b = wg*16+q*4+kk
        U2 rr = threefry(kA, kB, 0u, j);
        float nrm = jax_normal_from_bits(rr.x ^ rr.y);
        lat[kk] = fmaf(escale, nrm, lat[kk]);      // escale=0 at t=0
      }
    }

    // x for rows q*4..q*4+3 at time t: one broadcast ds_read_b128
    float4v xv = *(const float4v*)&x_tr[t * ROWS + q * 4];

    #pragma unroll
    for (int r = 0; r < 4; ++r) {
      float d = aa[r] + ab[r] * (1.0f / 2048.0f);
      float pre = d + fmaf(xv[r], wih, bias);
      float h;
      if (__builtin_fabsf(pre) >= 7.90531110763549805f) {
        h = pre > 0.0f ? 1.0f : -1.0f;     // XLA tanh clamp
      } else {
        float e = __builtin_amdgcn_exp2f(pre * 2.8853900817779268f);
        h = fmaf(-2.0f, __builtin_amdgcn_rcpf(e + 1.0f), 1.0f);
      }
      float nl = lat[r] + xv[r] + h;       // noise already folded into lat
      lat[r] = nl;
      _Float16 hh = (_Float16)nl;          // RNE
      _Float16 ll = (_Float16)((nl - (float)hh) * 2048.0f);
      short* wp = wb + r*LSTR;
      wp[0]    = __builtin_bit_cast(short, hh);
      wp[TILE] = __builtin_bit_cast(short, ll);
    }
    __syncthreads(); // single barrier/step (reads buf t&1, writes (t+1)&1)
  }

  #pragma unroll
  for (int r = 0; r < 4; ++r)
    out[jbase + ((unsigned)r << 8)] = lat[r];
}

extern "C" void kernel_launch(void* const* d_in, const int* in_sizes, int n_in,
                              void* d_out, int out_size, void* d_ws, size_t ws_size,
                              hipStream_t stream) {
  // inputs: [0]=T (int, =256), [1]=flat_img (4096x256 f32), [2]=W_ih (256x1),
  // [3]=W_hh (256x256), [4]=b_ih (256), [5]=b_hh (256)
  (void)in_sizes; (void)n_in; (void)out_size; (void)d_ws; (void)ws_size;
  const float* flat_img = (const float*)d_in[1];
  const float* W_ih     = (const float*)d_in[2];
  const float* W_hh     = (const float*)d_in[3];
  const float* b_ih     = (const float*)d_in[4];
  const float* b_hh     = (const float*)d_in[5];
  drnet_fused<<<dim3(4096 / ROWS), dim3(1024), 0, stream>>>(
      flat_img, W_ih, W_hh, b_ih, b_hh, (float*)d_out);
}